// Round 7
// baseline (45.973 us; speedup 1.0000x reference)
//
#include <hip/hip_runtime.h>
#include <math.h>

#define CROP 96
#define WIN 11
#define OUT 86          // CROP - WIN + 1
#define IMH 1080
#define IMW 1920
#define NIT 11          // chunks of 8 output rows
#define RSW 356         // words per row-slot: 88*4 + 4 pad -> 4 mod 32 (bank-rotating), 16B-aligned
#define NSLOT 32        // circular row buffer

typedef float v2f __attribute__((ext_vector_type(2)));

// LDS: hbuf[slot][x 0..87][4] = (P, Q, PP, QQ) — horizontal 11-tap conv of
// p=a+b, q=a-b, p^2, q^2 for input row `slot`, out-col x.
// A-tasks are anchored on the 16B-aligned grid xa = xmin - r (r = xmin&3):
// task g loads aligned cols [12g, 12g+24) and produces out-cols 12g-r+j.

__global__ __launch_bounds__(256) void ssim_kernel(
    const float* __restrict__ img,
    const float* __restrict__ imgr,
    const int* __restrict__ target,
    float* __restrict__ block_sums)
{
    __shared__ __align__(16) float hbuf[NSLOT * RSW];   // 45568 B
    __shared__ float red[256];

    const int blk = blockIdx.x;          // 0 .. 3N-1
    const int s   = blk / 3;
    const int c   = blk % 3;

    const int xmin = target[s * 5 + 0];
    const int ymin = target[s * 5 + 1];
    const int r    = xmin & 3;           // block-uniform alignment shift

    const size_t cbase = (size_t)c * (IMH * IMW) + (size_t)ymin * IMW + (size_t)(xmin - r);
    const float* __restrict__ pa = img  + cbase;   // 16B-aligned rows (IMW%4==0)
    const float* __restrict__ pb = imgr + cbase;

    const int tid = threadIdx.x;

    // gaussian weights (f32, matches reference)
    float gw[WIN];
    {
        float sum = 0.f;
        #pragma unroll
        for (int k = 0; k < WIN; ++k) {
            const float cc = (float)k - (float)(WIN - 1) * 0.5f;
            gw[k] = expf(-(cc * cc) / (2.0f * 1.5f * 1.5f));
            sum += gw[k];
        }
        const float inv = 1.0f / sum;
        #pragma unroll
        for (int k = 0; k < WIN; ++k) gw[k] *= inv;
    }

    // ---- horizontal 11-tap conv of one input row, aligned-window task ----
    auto doA_task = [&](int row, int g) {
        const int x0 = 12 * g;                         // xa-col anchor (16B-aligned)
        const float* __restrict__ ra = pa + (size_t)row * IMW + x0;
        const float* __restrict__ rb = pb + (size_t)row * IMW + x0;
        const int sbase = (row & (NSLOT - 1)) * RSW;

        if (g < 7) {
            float wa[24], wb[24];
            #pragma unroll
            for (int i = 0; i < 6; ++i) {              // aligned dwordx4, cols x0..x0+23 <= 95
                const float4 fa = *(const float4*)(ra + 4 * i);
                const float4 fb = *(const float4*)(rb + 4 * i);
                wa[4*i+0] = fa.x; wa[4*i+1] = fa.y; wa[4*i+2] = fa.z; wa[4*i+3] = fa.w;
                wb[4*i+0] = fb.x; wb[4*i+1] = fb.y; wb[4*i+2] = fb.z; wb[4*i+3] = fb.w;
            }
            v2f aPQ[12] = {}; v2f aP2[12] = {};
            #pragma unroll
            for (int tt = 0; tt < 22; ++tt) {
                const v2f pq  = {wa[tt] + wb[tt], wa[tt] - wb[tt]};
                const v2f pq2 = pq * pq;
                #pragma unroll
                for (int jj = 0; jj < 12; ++jj) {
                    const int kk = tt - jj;
                    if (kk >= 0 && kk < WIN) {
                        aPQ[jj] += pq  * gw[kk];       // v_pk_fma_f32
                        aP2[jj] += pq2 * gw[kk];
                    }
                }
            }
            #pragma unroll
            for (int jj = 0; jj < 12; ++jj) {
                const int x_out = x0 - r + jj;         // shifted partition
                if ((unsigned)x_out < 88u)
                    *(float4*)&hbuf[sbase + x_out * 4] =
                        make_float4(aPQ[jj].x, aPQ[jj].y, aP2[jj].x, aP2[jj].y);
            }
        } else {
            // tail task: aligned cols 84..95 (3 float4) + up to r scalars (cols 96..98),
            // all provably within the image row. Produces out-cols 84-r..90-r (7).
            float wa[17], wb[17];
            #pragma unroll
            for (int i = 0; i < 3; ++i) {
                const float4 fa = *(const float4*)(ra + 4 * i);
                const float4 fb = *(const float4*)(rb + 4 * i);
                wa[4*i+0] = fa.x; wa[4*i+1] = fa.y; wa[4*i+2] = fa.z; wa[4*i+3] = fa.w;
                wb[4*i+0] = fb.x; wb[4*i+1] = fb.y; wb[4*i+2] = fb.z; wb[4*i+3] = fb.w;
            }
            #pragma unroll
            for (int q = 0; q < 5; ++q) { wa[12+q] = 0.f; wb[12+q] = 0.f; }
            #pragma unroll
            for (int q = 0; q < 3; ++q) {
                if (q < r) { wa[12+q] = ra[12+q]; wb[12+q] = rb[12+q]; }
            }
            v2f aPQ[7] = {}; v2f aP2[7] = {};
            #pragma unroll
            for (int tt = 0; tt < 17; ++tt) {
                const v2f pq  = {wa[tt] + wb[tt], wa[tt] - wb[tt]};
                const v2f pq2 = pq * pq;
                #pragma unroll
                for (int jj = 0; jj < 7; ++jj) {
                    const int kk = tt - jj;
                    if (kk >= 0 && kk < WIN) {
                        aPQ[jj] += pq  * gw[kk];
                        aP2[jj] += pq2 * gw[kk];
                    }
                }
            }
            #pragma unroll
            for (int jj = 0; jj < 7; ++jj) {
                const int x_out = 84 - r + jj;         // >= 81
                if (x_out < 88)
                    *(float4*)&hbuf[sbase + x_out * 4] =
                        make_float4(aPQ[jj].x, aPQ[jj].y, aP2[jj].x, aP2[jj].y);
            }
        }
    };

    // ---- prologue: fill input rows 0..17 (18 rows x 8 groups = 144 tasks) ----
    if (tid < 144) doA_task(tid >> 3, tid & 7);
    __syncthreads();

    const float C1 = 6.5025f;
    const float C2 = 58.5225f;
    float acc = 0.f;

    // hoisted per-thread task coordinates
    const int bx    = (tid < 172) ? (tid % 86) : 0;    // B: out-col
    const int bgrp  = (tid < 172) ? (tid / 86) : 0;    // B: 4-row group 0/1
    const int au    = tid - 192;                       // A: 0..63 when tid>=192
    const int arow0 = (au >> 3) + 18;
    const int ag    = au & 7;

    for (int k = 0; k < NIT; ++k) {
        const int r0out = 8 * k;

        if (tid < 172) {
            // ---- B: vertical 11-tap conv + SSIM, 4 out-rows x 1 col ----
            const int r0 = r0out + bgrp * 4;
            v2f mPQ[4] = {}; v2f mP2[4] = {};
            #pragma unroll
            for (int tt = 0; tt < 14; ++tt) {
                const int slot = (r0 + tt) & (NSLOT - 1);
                const float4 f = *(const float4*)&hbuf[slot * RSW + bx * 4];
                const v2f fPQ = {f.x, f.y};
                const v2f fP2 = {f.z, f.w};
                #pragma unroll
                for (int jj = 0; jj < 4; ++jj) {
                    const int kk = tt - jj;
                    if (kk >= 0 && kk < WIN) {
                        mPQ[jj] += fPQ * gw[kk];
                        mP2[jj] += fP2 * gw[kk];
                    }
                }
            }
            #pragma unroll
            for (int jj = 0; jj < 4; ++jj) {
                if (r0 + jj < OUT) {
                    const v2f sq = mPQ[jj] * mPQ[jj];
                    const float mu12x2  = (sq.x - sq.y) * 0.5f;
                    const float musqsum = (sq.x + sq.y) * 0.5f;
                    const float e_dif = (mP2[jj].x - mP2[jj].y) * 0.5f;
                    const float e_sum = (mP2[jj].x + mP2[jj].y) * 0.5f;
                    const float s12x2 = e_dif - mu12x2;
                    const float ssum  = e_sum - musqsum;
                    const float num = (mu12x2 + C1) * (s12x2 + C2);
                    const float den = (musqsum + C1) * (ssum + C2);
                    acc += num * __builtin_amdgcn_rcpf(den);
                }
            }
        } else if (tid >= 192) {
            // ---- A: horizontal conv of next chunk's input rows ----
            const int row = r0out + arow0;             // 8k+18 .. 8k+25
            if (row < CROP) doA_task(row, ag);
        }
        __syncthreads();
    }

    // ---- deterministic block reduction ----
    red[tid] = acc;
    __syncthreads();
    #pragma unroll
    for (int off = 128; off > 0; off >>= 1) {
        if (tid < off) red[tid] += red[tid + off];
        __syncthreads();
    }
    if (tid == 0) block_sums[blk] = red[0];
}

__global__ __launch_bounds__(256) void ssim_finalize_kernel(
    const float* __restrict__ block_sums,
    float* __restrict__ out,
    int nblk,
    float inv_npix)
{
    __shared__ float red[256];
    const int tid = threadIdx.x;
    float s = 0.f;
    for (int i = tid; i < nblk; i += 256) s += block_sums[i];
    red[tid] = s;
    __syncthreads();
    #pragma unroll
    for (int off = 128; off > 0; off >>= 1) {
        if (tid < off) red[tid] += red[tid + off];
        __syncthreads();
    }
    if (tid == 0) {
        const float mean = red[0] * inv_npix;
        out[0] = 5.0f * (1.0f - mean);
    }
}

extern "C" void kernel_launch(void* const* d_in, const int* in_sizes, int n_in,
                              void* d_out, int out_size, void* d_ws, size_t ws_size,
                              hipStream_t stream)
{
    const float* img  = (const float*)d_in[0];
    const float* imgr = (const float*)d_in[1];
    const int*   tgt  = (const int*)d_in[2];
    const int N = in_sizes[2] / 5;
    const int nblk = 3 * N;

    float* block_sums = (float*)d_ws;
    const float inv_npix = 1.0f / ((float)nblk * (float)(OUT * OUT));

    ssim_kernel<<<nblk, 256, 0, stream>>>(img, imgr, tgt, block_sums);
    ssim_finalize_kernel<<<1, 256, 0, stream>>>(block_sums, (float*)d_out, nblk, inv_npix);
}

// Round 8
// 34.679 us; speedup vs baseline: 1.3257x; 1.3257x over previous
//
#include <hip/hip_runtime.h>
#include <math.h>

#define CROP 96
#define WIN 11
#define OUT 86          // CROP - WIN + 1
#define IMH 1080
#define IMW 1920
#define NIT 11          // chunks of 8 output rows: 86 = 10*8 + 6
#define RSW 356         // words per row-slot: 88*4 + 4 pad -> 4 mod 32 (bank-rotating)
#define NSLOT 32        // circular row buffer (power of 2)

typedef float v2f __attribute__((ext_vector_type(2)));

// LDS: hbuf[slot][x 0..87][4] = (P, Q, PP, QQ) — horizontal 11-tap conv of
// p=a+b, q=a-b, p^2, q^2 for input row `slot`, out-col x.
//
// Wave roles are ROTATED by blockIdx so the heavy A-wave of co-resident
// blocks lands on different SIMDs (wave->SIMD is wave_id%4): without this,
// all 3 resident blocks' A-waves pile on SIMD 3 while 0-2 idle at barriers.

__global__ __launch_bounds__(256) void ssim_kernel(
    const float* __restrict__ img,
    const float* __restrict__ imgr,
    const int* __restrict__ target,
    float* __restrict__ block_sums)
{
    __shared__ __align__(16) float hbuf[NSLOT * RSW];   // 45568 B
    __shared__ float red[256];

    const int blk = blockIdx.x;          // 0 .. 3N-1
    const int s   = blk / 3;
    const int c   = blk % 3;

    const int xmin = target[s * 5 + 0];
    const int ymin = target[s * 5 + 1];

    const size_t cbase = (size_t)c * (IMH * IMW) + (size_t)ymin * IMW + (size_t)xmin;
    const float* __restrict__ pa = img  + cbase;
    const float* __restrict__ pb = imgr + cbase;

    const int tid  = threadIdx.x;
    const int wave = tid >> 6;
    const int lane = tid & 63;
    const int vt   = (((wave + blk) & 3) << 6) | lane;   // rotated virtual tid

    // gaussian weights (f32, matches reference)
    float gw[WIN];
    {
        float sum = 0.f;
        #pragma unroll
        for (int k = 0; k < WIN; ++k) {
            const float cc = (float)k - (float)(WIN - 1) * 0.5f;
            gw[k] = expf(-(cc * cc) / (2.0f * 1.5f * 1.5f));
            sum += gw[k];
        }
        const float inv = 1.0f / sum;
        #pragma unroll
        for (int k = 0; k < WIN; ++k) gw[k] *= inv;
    }

    // ---- horizontal 11-tap conv of one input row, 12 out-cols, packed pairs ----
    auto doA_task = [&](int row, int g) {
        const int xo = (g == 7) ? 74 : 12 * g;         // window xo..xo+21 <= 95
        const float* __restrict__ ra = pa + (size_t)row * IMW + xo;
        const float* __restrict__ rb = pb + (size_t)row * IMW + xo;

        v2f aPQ[12] = {}; v2f aP2[12] = {};
        #pragma unroll
        for (int tt = 0; tt < 22; ++tt) {              // static offsets, no clamp
            const float a = ra[tt];
            const float b = rb[tt];
            const v2f pq  = {a + b, a - b};
            const v2f pq2 = pq * pq;
            #pragma unroll
            for (int jj = 0; jj < 12; ++jj) {
                const int kk = tt - jj;
                if (kk >= 0 && kk < WIN) {
                    aPQ[jj] += pq  * gw[kk];           // v_pk_fma_f32
                    aP2[jj] += pq2 * gw[kk];
                }
            }
        }
        const int sbase = (row & (NSLOT - 1)) * RSW;
        #pragma unroll
        for (int jj = 0; jj < 12; ++jj) {
            const int x = xo + jj;                     // g=7 overlaps g=6: bit-identical
            *(float4*)&hbuf[sbase + x * 4] =
                make_float4(aPQ[jj].x, aPQ[jj].y, aP2[jj].x, aP2[jj].y);
        }
    };

    // ---- prologue: fill input rows 0..17 (18 rows x 8 groups = 144 tasks) ----
    if (vt < 144) doA_task(vt >> 3, vt & 7);
    __syncthreads();

    const float C1 = 6.5025f;
    const float C2 = 58.5225f;
    float acc = 0.f;

    // hoisted per-thread task coordinates (virtual-tid based)
    const int bx    = (vt < 172) ? (vt % 86) : 0;      // B: out-col
    const int bgrp  = (vt < 172) ? (vt / 86) : 0;      // B: 4-row group 0/1
    const int au    = vt - 192;                        // A: 0..63 when vt>=192
    const int arow0 = (au >> 3) + 18;
    const int ag    = au & 7;

    for (int k = 0; k < NIT; ++k) {
        const int r0out = 8 * k;

        if (vt < 172) {
            // ---- B: vertical 11-tap conv + SSIM, 4 out-rows x 1 col ----
            const int r0 = r0out + bgrp * 4;
            v2f mPQ[4] = {}; v2f mP2[4] = {};
            #pragma unroll
            for (int tt = 0; tt < 14; ++tt) {          // rows r0..r0+13 cover 4 out-rows
                const int slot = (r0 + tt) & (NSLOT - 1);
                const float4 f = *(const float4*)&hbuf[slot * RSW + bx * 4];
                const v2f fPQ = {f.x, f.y};
                const v2f fP2 = {f.z, f.w};
                #pragma unroll
                for (int jj = 0; jj < 4; ++jj) {
                    const int kk = tt - jj;
                    if (kk >= 0 && kk < WIN) {
                        mPQ[jj] += fPQ * gw[kk];       // v_pk_fma_f32
                        mP2[jj] += fP2 * gw[kk];
                    }
                }
            }
            #pragma unroll
            for (int jj = 0; jj < 4; ++jj) {
                if (r0 + jj < OUT) {
                    const v2f sq = mPQ[jj] * mPQ[jj];          // {P^2, Q^2}
                    const float mu12x2  = (sq.x - sq.y) * 0.5f;       // 2*mu1*mu2
                    const float musqsum = (sq.x + sq.y) * 0.5f;       // mu1^2+mu2^2
                    const float e_dif = (mP2[jj].x - mP2[jj].y) * 0.5f; // 2*E[ab]
                    const float e_sum = (mP2[jj].x + mP2[jj].y) * 0.5f; // E[a^2]+E[b^2]
                    const float s12x2 = e_dif - mu12x2;
                    const float ssum  = e_sum - musqsum;
                    const float num = (mu12x2 + C1) * (s12x2 + C2);
                    const float den = (musqsum + C1) * (ssum + C2);
                    acc += num * __builtin_amdgcn_rcpf(den);
                }
            }
        } else if (vt >= 192) {
            // ---- A: horizontal conv of next chunk's input rows ----
            const int row = r0out + arow0;             // 8k+18 .. 8k+25
            if (row < CROP) doA_task(row, ag);
        }
        __syncthreads();
    }

    // ---- deterministic block reduction ----
    red[tid] = acc;
    __syncthreads();
    #pragma unroll
    for (int off = 128; off > 0; off >>= 1) {
        if (tid < off) red[tid] += red[tid + off];
        __syncthreads();
    }
    if (tid == 0) block_sums[blk] = red[0];
}

__global__ __launch_bounds__(256) void ssim_finalize_kernel(
    const float* __restrict__ block_sums,
    float* __restrict__ out,
    int nblk,
    float inv_npix)
{
    __shared__ float red[256];
    const int tid = threadIdx.x;
    float s = 0.f;
    for (int i = tid; i < nblk; i += 256) s += block_sums[i];
    red[tid] = s;
    __syncthreads();
    #pragma unroll
    for (int off = 128; off > 0; off >>= 1) {
        if (tid < off) red[tid] += red[tid + off];
        __syncthreads();
    }
    if (tid == 0) {
        const float mean = red[0] * inv_npix;
        out[0] = 5.0f * (1.0f - mean);
    }
}

extern "C" void kernel_launch(void* const* d_in, const int* in_sizes, int n_in,
                              void* d_out, int out_size, void* d_ws, size_t ws_size,
                              hipStream_t stream)
{
    const float* img  = (const float*)d_in[0];
    const float* imgr = (const float*)d_in[1];
    const int*   tgt  = (const int*)d_in[2];
    const int N = in_sizes[2] / 5;
    const int nblk = 3 * N;

    float* block_sums = (float*)d_ws;
    const float inv_npix = 1.0f / ((float)nblk * (float)(OUT * OUT));

    ssim_kernel<<<nblk, 256, 0, stream>>>(img, imgr, tgt, block_sums);
    ssim_finalize_kernel<<<1, 256, 0, stream>>>(block_sums, (float*)d_out, nblk, inv_npix);
}